// Round 6
// baseline (215.516 us; speedup 1.0000x reference)
//
#include <hip/hip_runtime.h>
#include <math.h>

typedef __attribute__((ext_vector_type(8))) __bf16 bf16x8;
typedef __attribute__((ext_vector_type(8))) unsigned short us8;
typedef __attribute__((ext_vector_type(4))) unsigned short us4;
typedef __attribute__((ext_vector_type(4))) float f32x4;
typedef __attribute__((ext_vector_type(4))) int i32x4;
typedef unsigned int uint32;

#define EPSV 1e-5f

__device__ __forceinline__ float silu_f(float v) { return v / (1.f + __expf(-v)); }

__device__ __forceinline__ unsigned short f2bf(float f) {
  uint32 u = __builtin_bit_cast(uint32, f);
  u += 0x7fffu + ((u >> 16) & 1u);   // RNE
  return (unsigned short)(u >> 16);
}
__device__ __forceinline__ float bf2f(unsigned short h) {
  uint32 u = ((uint32)h) << 16;
  return __builtin_bit_cast(float, u);
}

// async global->LDS DMA, 16B per lane. LDS dest = wave-uniform base + lane*16.
__device__ __forceinline__ void gl_lds16(const void* g, void* l) {
  __builtin_amdgcn_global_load_lds(
      (const __attribute__((address_space(1))) unsigned int*)g,
      (__attribute__((address_space(3))) unsigned int*)l, 16, 0, 0);
}

// ---------------------------------------------------------------------------
// NCHW f32 -> NHWC bf16 tokens (N,4096,256), via LDS transpose.
// ---------------------------------------------------------------------------
__global__ __launch_bounds__(256) void nchw_to_tok(const float* __restrict__ x,
                                                   unsigned short* __restrict__ xt) {
  __shared__ float lds[64][65];
  const int p0 = blockIdx.x * 64, c0 = blockIdx.y * 64, n = blockIdx.z;
  const int t = threadIdx.x;
  const int pp = t & 63, ccb = t >> 6;
  const float* xb = x + ((size_t)n * 256 + c0) * 4096 + p0;
#pragma unroll
  for (int i = 0; i < 16; i++) {
    int cc = ccb * 16 + i;
    lds[pp][cc] = xb[(size_t)cc * 4096 + pp];
  }
  __syncthreads();
#pragma unroll
  for (int i = 0; i < 2; i++) {
    int pp2 = (t >> 3) + i * 32;
    int c8 = (t & 7) * 8;
    us8 v;
#pragma unroll
    for (int j = 0; j < 8; j++) v[j] = f2bf(lds[pp2][c8 + j]);
    *(us8*)&xt[((size_t)(n * 4096 + p0 + pp2)) * 256 + c0 + c8] = v;
  }
}

// ---------------------------------------------------------------------------
// out = x + y2 + d  (tokens bf16 -> NCHW f32), via LDS transpose.
// ---------------------------------------------------------------------------
__global__ __launch_bounds__(256) void fuse_out_k(
    const float* __restrict__ x, const unsigned short* __restrict__ y2t,
    const unsigned short* __restrict__ dt, float* __restrict__ out) {
  __shared__ float lds[64][65];
  const int p0 = blockIdx.x * 64, c0 = blockIdx.y * 64, n = blockIdx.z;
  const int t = threadIdx.x;
#pragma unroll
  for (int i = 0; i < 2; i++) {
    int pp = (t >> 3) + i * 32;
    int c8 = (t & 7) * 8;
    size_t base = ((size_t)(n * 4096 + p0 + pp)) * 256 + c0 + c8;
    us8 a = *(const us8*)&y2t[base];
    us8 b = *(const us8*)&dt[base];
#pragma unroll
    for (int j = 0; j < 8; j++) lds[pp][c8 + j] = bf2f(a[j]) + bf2f(b[j]);
  }
  __syncthreads();
  const int pp2 = t & 63, ccb = t >> 6;
  const size_t nco = ((size_t)n * 256 + c0) * 4096 + p0;
#pragma unroll
  for (int i = 0; i < 16; i++) {
    int cc = ccb * 16 + i;
    size_t idx = nco + (size_t)cc * 4096 + pp2;
    out[idx] = x[idx] + lds[pp2][cc];
  }
}

// ---------------------------------------------------------------------------
// All weight conversions in ONE launch (+ zero-page init).
// conv weights: (Co,Ci,3,3) f32 -> (Co, 9*Ci) bf16 with k = tap*Ci + ci
// ---------------------------------------------------------------------------
__global__ void cvt_all(
    const float* __restrict__ c1, unsigned short* __restrict__ o1,
    const float* __restrict__ c2, unsigned short* __restrict__ o2,
    const float* __restrict__ a0, unsigned short* __restrict__ b0,
    const float* __restrict__ a1, unsigned short* __restrict__ b1,
    const float* __restrict__ a2, unsigned short* __restrict__ b2,
    const float* __restrict__ a3, unsigned short* __restrict__ b3,
    const float* __restrict__ a4, unsigned short* __restrict__ b4,
    uint32* __restrict__ zp) {
  if (blockIdx.x == 0 && threadIdx.x < 32) zp[threadIdx.x] = 0u;
  int idx = blockIdx.x * 256 + threadIdx.x;
  if (idx < 294912) {
    int ci = idx & 255, r = idx >> 8;
    int tap = r % 9, co = r / 9;
    o1[idx] = f2bf(c1[((size_t)co * 256 + ci) * 9 + tap]);
    return;
  }
  idx -= 294912;
  if (idx < 294912) {
    int ci = idx & 127, r = idx >> 7;
    int tap = r % 9, co = r / 9;
    o2[idx] = f2bf(c2[((size_t)co * 128 + ci) * 9 + tap]);
    return;
  }
  idx -= 294912;
  const float* s;
  unsigned short* d;
  int off;
  if (idx < 65536)       { s = a0; d = b0; off = idx; }
  else if (idx < 120832) { s = a1; d = b1; off = idx - 65536; }
  else if (idx < 186368) { s = a2; d = b2; off = idx - 120832; }
  else if (idx < 382976) { s = a3; d = b3; off = idx - 186368; }
  else if (idx < 579584) { s = a4; d = b4; off = idx - 382976; }
  else return;
  d[off] = f2bf(s[off]);
}

// ---------------------------------------------------------------------------
// Unified bf16 MFMA GEMM, 64x64 tile, 4 waves (each 32x32 out), BK=64.
// Ring-3 LDS buffers staged via global_load_lds (16B/lane), depth-2 prefetch
// with COUNTED vmcnt (T3+T4): per iter wait vmcnt(4) (current tile's 4 DMA
// instructions done; next tile's 4 remain in flight across the barrier),
// raw s_barrier, issue tile it+2, compute. Only the last iter drains to 0.
//   A: tokens (16384, K) bf16; CONV (CIN>0): K = 9*CIN, implicit im2col;
//      OOB taps / cols read a 64B zero page.
//   B: (Co, K) bf16 row-major.
// LDS fragment-major: chunk id = ((sub*2+ks)*64 + kg*16 + idx16); stage
// writes and frag reads are lane-linear 1024B sweeps (conflict-free, and
// exactly the wave-uniform-base + lane*16 pattern global_load_lds needs).
// EPI: 0 = bias->bf16 | 1 = bias->f32 | 2 = BN+SiLU->bf16 (no bias)
//      3 = bias+BN->bf16 | 4 = bias+SiLU->bf16
//      5 = split val/om: col<256 -> bf16 outv (stride 256, bias=bias);
//          col>=256  -> f32 (float*)e1 (stride 216, bias=e0[col-256])
// ---------------------------------------------------------------------------
template <int EPI, int CIN>
__global__ __launch_bounds__(256) void mfma_gemm(
    const unsigned short* __restrict__ A, const unsigned short* __restrict__ Bw,
    const float* __restrict__ bias, int K, int Co, void* __restrict__ outv,
    const float* __restrict__ e0, const float* __restrict__ e1,
    const float* __restrict__ e2, const float* __restrict__ e3,
    const unsigned short* __restrict__ zpage) {
  __shared__ bf16x8 smem[3072];  // 3 ring slots x [A 512 | B 512] = 48 KB
  const int t = threadIdx.x;
  const int lane = t & 63;
  const int wv = t >> 6;
  const int wr = wv >> 1, wc = wv & 1;
  const int rb = blockIdx.y * 64, cb = blockIdx.x * 64;

  f32x4 acc[2][2];
#pragma unroll
  for (int i = 0; i < 2; i++)
#pragma unroll
    for (int j = 0; j < 2; j++) acc[i][j] = (f32x4){0.f, 0.f, 0.f, 0.f};

  auto addrA = [&](int c, int kb) -> const unsigned short* {
    int row16 = c & 15, kg = (c >> 4) & 3, ks = (c >> 6) & 1, msub = c >> 7;
    int row = msub * 16 + row16;
    int koff = ks * 32 + kg * 8;
    if constexpr (CIN > 0) {
      int tap = kb / CIN, ci = kb % CIN + koff;
      int dy = tap / 3 - 1, dx = tap % 3 - 1;
      int grow = rb + row;
      int n = grow >> 12, p = grow & 4095;
      int h = (p >> 6) + dy, w = (p & 63) + dx;
      if (((unsigned)h < 64u) && ((unsigned)w < 64u))
        return &A[((size_t)(n * 4096 + h * 64 + w)) * CIN + ci];
      return zpage;
    } else {
      return &A[(size_t)(rb + row) * K + kb + koff];
    }
  };
  auto addrB = [&](int c, int kb) -> const unsigned short* {
    int col16 = c & 15, kg = (c >> 4) & 3, ks = (c >> 6) & 1, csub = c >> 7;
    int col = cb + csub * 16 + col16;
    int koff = ks * 32 + kg * 8;
    return (col < Co) ? &Bw[(size_t)col * K + kb + koff] : zpage;
  };
  auto stage = [&](int slot, int kb) {
    bf16x8* base = &smem[slot * 1024];
    gl_lds16(addrA(t, kb), (void*)&base[t]);
    gl_lds16(addrA(t + 256, kb), (void*)&base[t + 256]);
    gl_lds16(addrB(t, kb), (void*)&base[512 + t]);
    gl_lds16(addrB(t + 256, kb), (void*)&base[512 + t + 256]);
  };

  const int nt = K >> 6;
  stage(0, 0);
  if (nt > 1) stage(1, 64);
  int cur = 0;
  for (int it = 0; it < nt; ++it) {
    // counted wait: current tile's 4 loads done, next tile's stay in flight
    if (it + 1 < nt) {
      asm volatile("s_waitcnt vmcnt(4)" ::: "memory");
    } else {
      asm volatile("s_waitcnt vmcnt(0)" ::: "memory");
    }
    __builtin_amdgcn_s_barrier();
    asm volatile("" ::: "memory");
    if (it + 2 < nt) {
      int nslot = cur + 2;
      if (nslot >= 3) nslot -= 3;
      stage(nslot, (it + 2) << 6);
    }
    const bf16x8* Ab = &smem[cur * 1024];
    const bf16x8* Bb = Ab + 512;
    __builtin_amdgcn_s_setprio(1);
#pragma unroll
    for (int ks = 0; ks < 2; ks++) {
      bf16x8 af[2], bfr[2];
#pragma unroll
      for (int mi = 0; mi < 2; mi++) af[mi] = Ab[((wr * 2 + mi) * 2 + ks) * 64 + lane];
#pragma unroll
      for (int ni = 0; ni < 2; ni++) bfr[ni] = Bb[((wc * 2 + ni) * 2 + ks) * 64 + lane];
#pragma unroll
      for (int mi = 0; mi < 2; mi++)
#pragma unroll
        for (int ni = 0; ni < 2; ni++)
          acc[mi][ni] = __builtin_amdgcn_mfma_f32_16x16x32_bf16(af[mi], bfr[ni],
                                                                acc[mi][ni], 0, 0, 0);
    }
    __builtin_amdgcn_s_setprio(0);
    asm volatile("" ::: "memory");
    cur = (cur + 1 == 3) ? 0 : cur + 1;
  }

  // ---- epilogue.  C/D: col = lane&15, row = (lane>>4)*4 + reg
  const int lr = lane & 15, kg4 = (lane >> 4) * 4;
#pragma unroll
  for (int mi = 0; mi < 2; mi++) {
#pragma unroll
    for (int ni = 0; ni < 2; ni++) {
      int gcol = cb + wc * 32 + ni * 16 + lr;
      if (gcol >= Co) continue;
      float bval, s = 1.f, tt = 0.f;
      if (EPI == 2) bval = 0.f;
      else if (EPI == 5) bval = (gcol < 256) ? bias[gcol] : e0[gcol - 256];
      else bval = bias[gcol];
      if (EPI == 2 || EPI == 3) {
        s = e0[gcol] * rsqrtf(e3[gcol] + EPSV);
        tt = e1[gcol] - e2[gcol] * s;
      }
#pragma unroll
      for (int j = 0; j < 4; j++) {
        int grow = rb + wr * 32 + mi * 16 + kg4 + j;
        float v = acc[mi][ni][j] + bval;
        if (EPI == 2) v = silu_f(v * s + tt);
        if (EPI == 3) v = v * s + tt;
        if (EPI == 4) v = silu_f(v);
        if (EPI == 1) {
          ((float*)outv)[(size_t)grow * Co + gcol] = v;
        } else if (EPI == 5) {
          if (gcol < 256)
            ((unsigned short*)outv)[(size_t)grow * 256 + gcol] = f2bf(v);
          else
            ((float*)e1)[(size_t)grow * 216 + (gcol - 256)] = v;
        } else {
          ((unsigned short*)outv)[(size_t)grow * Co + gcol] = f2bf(v);
        }
      }
    }
  }
}

// ---------------------------------------------------------------------------
// DCNv4 core v2 (two-phase).  value: bf16 tokens (N,4096,256),
// om: f32 tokens (N,4096,216), out: bf16 tokens.
// ---------------------------------------------------------------------------
__global__ __launch_bounds__(256) void dcn_core2(
    const unsigned short* __restrict__ value, const float* __restrict__ om,
    unsigned short* __restrict__ out) {
  __shared__ f32x4 wgt[288];
  __shared__ i32x4 adr[288];
  const int n = blockIdx.y;
  const int p0 = blockIdx.x * 4;
  const int t = threadIdx.x;

  for (int idx = t; idx < 288; idx += 256) {
    int pi = idx / 72;
    int gk = idx - pi * 72;
    int g = gk / 9, k = gk - g * 9;
    int p = p0 + pi;
    int h0 = p >> 6, w0 = p & 63;
    const float* omp = om + ((size_t)(n * 4096 + p)) * 216 + g * 27;
    float ox = omp[2 * k], oy = omp[2 * k + 1], mk = omp[18 + k];
    float px = (float)(w0 + (k % 3) - 1) + ox;
    float py = (float)(h0 + (k / 3) - 1) + oy;
    float x0f = floorf(px), y0f = floorf(py);
    float lx = px - x0f, ly = py - y0f;
    int x0 = (int)x0f, y0 = (int)y0f;
    int x1 = x0 + 1, y1 = y0 + 1;
    bool vx0 = (unsigned)x0 < 64u, vx1 = (unsigned)x1 < 64u;
    bool vy0 = (unsigned)y0 < 64u, vy1 = (unsigned)y1 < 64u;
    int cx0 = min(max(x0, 0), 63), cx1 = min(max(x1, 0), 63);
    int cy0 = min(max(y0, 0), 63), cy1 = min(max(y1, 0), 63);
    f32x4 w4;
    w4[0] = (1.f - ly) * (1.f - lx) * mk * (float)(vy0 && vx0);
    w4[1] = (1.f - ly) * lx * mk * (float)(vy0 && vx1);
    w4[2] = ly * (1.f - lx) * mk * (float)(vy1 && vx0);
    w4[3] = ly * lx * mk * (float)(vy1 && vx1);
    i32x4 a4;
    a4[0] = (cy0 * 64 + cx0) * 256;
    a4[1] = (cy0 * 64 + cx1) * 256;
    a4[2] = (cy1 * 64 + cx0) * 256;
    a4[3] = (cy1 * 64 + cx1) * 256;
    wgt[idx] = w4;
    adr[idx] = a4;
  }
  __syncthreads();

  const int pi = t >> 6;
  const int g = (t >> 3) & 7;
  const int l = t & 7;
  const int p = p0 + pi;
  const unsigned short* vb = value + ((size_t)n * 4096) * 256 + g * 32 + l * 4;
  const int bix = (pi * 8 + g) * 9;
  float a0 = 0.f, a1 = 0.f, a2 = 0.f, a3 = 0.f;
#pragma unroll
  for (int k = 0; k < 9; k++) {
    f32x4 wv = wgt[bix + k];
    i32x4 av = adr[bix + k];
    us4 q0 = *(const us4*)(vb + av[0]);
    us4 q1 = *(const us4*)(vb + av[1]);
    us4 q2 = *(const us4*)(vb + av[2]);
    us4 q3 = *(const us4*)(vb + av[3]);
    a0 += wv[0] * bf2f(q0[0]) + wv[1] * bf2f(q1[0]) + wv[2] * bf2f(q2[0]) + wv[3] * bf2f(q3[0]);
    a1 += wv[0] * bf2f(q0[1]) + wv[1] * bf2f(q1[1]) + wv[2] * bf2f(q2[1]) + wv[3] * bf2f(q3[1]);
    a2 += wv[0] * bf2f(q0[2]) + wv[1] * bf2f(q1[2]) + wv[2] * bf2f(q2[2]) + wv[3] * bf2f(q3[2]);
    a3 += wv[0] * bf2f(q0[3]) + wv[1] * bf2f(q1[3]) + wv[2] * bf2f(q2[3]) + wv[3] * bf2f(q3[3]);
  }
  us4 o;
  o[0] = f2bf(a0); o[1] = f2bf(a1); o[2] = f2bf(a2); o[3] = f2bf(a3);
  *(us4*)&out[((size_t)(n * 4096 + p)) * 256 + g * 32 + l * 4] = o;
}

// ---------------------------------------------------------------------------
extern "C" void kernel_launch(void* const* d_in, const int* in_sizes, int n_in,
                              void* d_out, int out_size, void* d_ws,
                              size_t ws_size, hipStream_t stream) {
  const float* x      = (const float*)d_in[0];
  const float* cv1_w  = (const float*)d_in[1];
  const float* cv1_g  = (const float*)d_in[2];
  const float* cv1_b  = (const float*)d_in[3];
  const float* cv1_m  = (const float*)d_in[4];
  const float* cv1_v  = (const float*)d_in[5];
  const float* cv2_w  = (const float*)d_in[6];
  const float* cv2_g  = (const float*)d_in[7];
  const float* cv2_b  = (const float*)d_in[8];
  const float* cv2_m  = (const float*)d_in[9];
  const float* cv2_v  = (const float*)d_in[10];
  const float* val_w  = (const float*)d_in[11];
  const float* val_b  = (const float*)d_in[12];
  const float* om_w   = (const float*)d_in[13];
  const float* om_b   = (const float*)d_in[14];
  const float* outp_w = (const float*)d_in[15];
  const float* outp_b = (const float*)d_in[16];
  const float* bn3_g  = (const float*)d_in[17];
  const float* bn3_b  = (const float*)d_in[18];
  const float* bn3_m  = (const float*)d_in[19];
  const float* bn3_v  = (const float*)d_in[20];
  const float* pw1_w  = (const float*)d_in[21];
  const float* pw1_b  = (const float*)d_in[22];
  const float* pw2_w  = (const float*)d_in[23];
  const float* pw2_b  = (const float*)d_in[24];
  float* out = (float*)d_out;

  char* w = (char*)d_ws;
  auto alloc = [&](size_t bytes) {
    char* p = w;
    w += (bytes + 255) & ~(size_t)255;
    return p;
  };
  unsigned short* xt    = (unsigned short*)alloc(16384ull * 256 * 2);
  unsigned short* y1t   = (unsigned short*)alloc(16384ull * 128 * 2);
  unsigned short* y2t   = (unsigned short*)alloc(16384ull * 256 * 2);
  unsigned short* valt  = (unsigned short*)alloc(16384ull * 256 * 2);
  float*          omf   = (float*)alloc(16384ull * 216 * 4);
  unsigned short* dcnt  = (unsigned short*)alloc(16384ull * 256 * 2);
  unsigned short* d1t   = (unsigned short*)alloc(16384ull * 256 * 2);
  unsigned short* p1t   = (unsigned short*)alloc(16384ull * 768 * 2);
  unsigned short* dt    = (unsigned short*)alloc(16384ull * 256 * 2);
  unsigned short* wc1   = (unsigned short*)alloc(128ull * 2304 * 2);
  unsigned short* wc2   = (unsigned short*)alloc(256ull * 1152 * 2);
  // wval and wom MUST be contiguous (fused val/om GEMM B-matrix, 472 x 256):
  unsigned short* wval  = (unsigned short*)alloc(256ull * 256 * 2);   // 256-mult
  unsigned short* wom   = (unsigned short*)alloc(216ull * 256 * 2);   // = wval + 65536
  unsigned short* woutp = (unsigned short*)alloc(256ull * 256 * 2);
  unsigned short* wpw1  = (unsigned short*)alloc(768ull * 256 * 2);
  unsigned short* wpw2  = (unsigned short*)alloc(256ull * 768 * 2);
  unsigned short* zpage = (unsigned short*)alloc(256);  // 64B zeros (+pad)

  // conversions (2 launches)
  nchw_to_tok<<<dim3(64, 4, 4), 256, 0, stream>>>(x, xt);
  cvt_all<<<4568, 256, 0, stream>>>(cv1_w, wc1, cv2_w, wc2, val_w, wval, om_w, wom,
                                    outp_w, woutp, pw1_w, wpw1, pw2_w, wpw2,
                                    (uint32*)zpage);

  // y path (convs as implicit GEMM)
  mfma_gemm<2, 256><<<dim3(2, 256), 256, 0, stream>>>(
      xt, wc1, nullptr, 2304, 128, y1t, cv1_g, cv1_b, cv1_m, cv1_v, zpage);
  mfma_gemm<2, 128><<<dim3(4, 256), 256, 0, stream>>>(
      y1t, wc2, nullptr, 1152, 256, y2t, cv2_g, cv2_b, cv2_m, cv2_v, zpage);

  // dcn path: fused val+om projection (B rows 0-255 = val_w, 256-471 = om_w)
  mfma_gemm<5, 0><<<dim3(8, 256), 256, 0, stream>>>(
      xt, wval, val_b, 256, 472, valt, om_b, omf, nullptr, nullptr, zpage);
  dcn_core2<<<dim3(1024, 4), 256, 0, stream>>>(valt, omf, dcnt);
  mfma_gemm<3, 0><<<dim3(4, 256), 256, 0, stream>>>(
      dcnt, woutp, outp_b, 256, 256, d1t, bn3_g, bn3_b, bn3_m, bn3_v, zpage);
  mfma_gemm<4, 0><<<dim3(12, 256), 256, 0, stream>>>(
      d1t, wpw1, pw1_b, 256, 768, p1t, nullptr, nullptr, nullptr, nullptr, zpage);
  mfma_gemm<0, 0><<<dim3(4, 256), 256, 0, stream>>>(
      p1t, wpw2, pw2_b, 768, 256, dt, nullptr, nullptr, nullptr, nullptr, zpage);

  // out = x + y2 + d
  fuse_out_k<<<dim3(64, 4, 4), 256, 0, stream>>>(x, y2t, dt, out);
}

// Round 7
// 192.643 us; speedup vs baseline: 1.1187x; 1.1187x over previous
//
#include <hip/hip_runtime.h>
#include <math.h>

typedef __attribute__((ext_vector_type(8))) __bf16 bf16x8;
typedef __attribute__((ext_vector_type(8))) unsigned short us8;
typedef __attribute__((ext_vector_type(4))) unsigned short us4;
typedef __attribute__((ext_vector_type(4))) float f32x4;
typedef __attribute__((ext_vector_type(4))) int i32x4;
typedef unsigned int uint32;

#define EPSV 1e-5f

__device__ __forceinline__ float silu_f(float v) { return v / (1.f + __expf(-v)); }

__device__ __forceinline__ unsigned short f2bf(float f) {
  uint32 u = __builtin_bit_cast(uint32, f);
  u += 0x7fffu + ((u >> 16) & 1u);   // RNE
  return (unsigned short)(u >> 16);
}
__device__ __forceinline__ float bf2f(unsigned short h) {
  uint32 u = ((uint32)h) << 16;
  return __builtin_bit_cast(float, u);
}

// async global->LDS DMA, 16B per lane. LDS dest = wave-uniform base + lane*16.
__device__ __forceinline__ void gl_lds16(const void* g, void* l) {
  __builtin_amdgcn_global_load_lds(
      (const __attribute__((address_space(1))) unsigned int*)g,
      (__attribute__((address_space(3))) unsigned int*)l, 16, 0, 0);
}

// ---------------------------------------------------------------------------
// GEMM body (round-5 proven dbuf structure), callable from fused kernels.
// 64x64 tile, 4 waves (each 32x32), BK=64, global_load_lds staging.
// LDS fragment-major: chunk id = ((sub*2+ks)*64 + kg*16 + idx16).
// EPI: 0 bias->bf16 | 1 bias->f32 | 2 BN+SiLU->bf16 | 3 bias+BN->bf16
//      4 bias+SiLU->bf16 | 5 split val/om | 6 bias + x + y2 -> NCHW f32
// ---------------------------------------------------------------------------
template <int EPI, int CIN>
__device__ __forceinline__ void gemm_body(
    int rb, int cb,
    const unsigned short* __restrict__ A, const unsigned short* __restrict__ Bw,
    const float* __restrict__ bias, int K, int Co, void* __restrict__ outv,
    const float* __restrict__ e0, const float* __restrict__ e1,
    const float* __restrict__ e2, const float* __restrict__ e3,
    const unsigned short* __restrict__ zpage, bf16x8* smem) {
  const int t = threadIdx.x;
  const int lane = t & 63;
  const int wv = t >> 6;
  const int wr = wv >> 1, wc = wv & 1;

  f32x4 acc[2][2];
#pragma unroll
  for (int i = 0; i < 2; i++)
#pragma unroll
    for (int j = 0; j < 2; j++) acc[i][j] = (f32x4){0.f, 0.f, 0.f, 0.f};

  // ---- hoisted per-chunk addressing state (2 chunks: c = t, t+256)
  const unsigned short* Abase[2];
  int aprow[2], apcol[2], akoff[2];
  const unsigned short* Bbase[2];
#pragma unroll
  for (int i = 0; i < 2; i++) {
    int c = t + 256 * i;
    int row16 = c & 15, kg = (c >> 4) & 3, ks = (c >> 6) & 1, sub = c >> 7;
    int row = sub * 16 + row16;
    int koff = ks * 32 + kg * 8;
    akoff[i] = koff;
    int grow = rb + row;
    if constexpr (CIN > 0) {
      int n = grow >> 12, p = grow & 4095;
      aprow[i] = p >> 6;
      apcol[i] = p & 63;
      Abase[i] = A + (size_t)n * 4096 * CIN;
    } else {
      Abase[i] = A + (size_t)grow * K + koff;
    }
    int col = cb + sub * 16 + row16;  // same decomposition for B
    Bbase[i] = (col < Co) ? (Bw + (size_t)col * K + koff) : zpage;
  }
  auto addrA = [&](int i, int kb) -> const unsigned short* {
    if constexpr (CIN > 0) {
      int tap = kb / CIN;
      int ci = (kb & (CIN - 1)) + akoff[i];
      int dy = tap / 3 - 1, dx = tap % 3 - 1;
      int h = aprow[i] + dy, w = apcol[i] + dx;
      if (((unsigned)h < 64u) & ((unsigned)w < 64u))
        return &Abase[i][(size_t)(h * 64 + w) * CIN + ci];
      return zpage;
    } else {
      return Abase[i] + kb;
    }
  };
  auto addrB = [&](int i, int kb) -> const unsigned short* {
    return (Bbase[i] == zpage) ? zpage : Bbase[i] + kb;
  };
  auto stage = [&](int buf, int kb) {
    bf16x8* base = &smem[buf * 1024];
    gl_lds16(addrA(0, kb), (void*)&base[t]);
    gl_lds16(addrA(1, kb), (void*)&base[t + 256]);
    gl_lds16(addrB(0, kb), (void*)&base[512 + t]);
    gl_lds16(addrB(1, kb), (void*)&base[512 + t + 256]);
  };

  const int nt = K >> 6;
  stage(0, 0);
  __syncthreads();
  int cur = 0;
  for (int it = 0; it < nt; ++it) {
    if (it + 1 < nt) stage(cur ^ 1, (it + 1) << 6);
    const bf16x8* Ab = &smem[cur * 1024];
    const bf16x8* Bb = Ab + 512;
    __builtin_amdgcn_s_setprio(1);
#pragma unroll
    for (int ks = 0; ks < 2; ks++) {
      bf16x8 af[2], bfr[2];
#pragma unroll
      for (int mi = 0; mi < 2; mi++) af[mi] = Ab[((wr * 2 + mi) * 2 + ks) * 64 + lane];
#pragma unroll
      for (int ni = 0; ni < 2; ni++) bfr[ni] = Bb[((wc * 2 + ni) * 2 + ks) * 64 + lane];
#pragma unroll
      for (int mi = 0; mi < 2; mi++)
#pragma unroll
        for (int ni = 0; ni < 2; ni++)
          acc[mi][ni] = __builtin_amdgcn_mfma_f32_16x16x32_bf16(af[mi], bfr[ni],
                                                                acc[mi][ni], 0, 0, 0);
    }
    __builtin_amdgcn_s_setprio(0);
    __syncthreads();
    cur ^= 1;
  }

  // ---- epilogue.  C/D: col = lane&15, row = (lane>>4)*4 + reg
  const int lr = lane & 15, kg4 = (lane >> 4) * 4;
#pragma unroll
  for (int mi = 0; mi < 2; mi++) {
#pragma unroll
    for (int ni = 0; ni < 2; ni++) {
      int gcol = cb + wc * 32 + ni * 16 + lr;
      if (gcol >= Co) continue;
      float bval, s = 1.f, tt = 0.f;
      if (EPI == 2) bval = 0.f;
      else if (EPI == 5) bval = (gcol < 256) ? bias[gcol] : e0[gcol - 256];
      else bval = bias[gcol];
      if (EPI == 2 || EPI == 3) {
        s = e0[gcol] * rsqrtf(e3[gcol] + EPSV);
        tt = e1[gcol] - e2[gcol] * s;
      }
      if (EPI == 6) {
        int grow0 = rb + wr * 32 + mi * 16 + kg4;
        int n = grow0 >> 12, p0 = grow0 & 4095;
        size_t oix = ((size_t)(n * 256 + gcol)) * 4096 + p0;
        f32x4 xv = *(const f32x4*)&((const float*)e0)[oix];
        const unsigned short* y2p = (const unsigned short*)e1;
        f32x4 ov;
#pragma unroll
        for (int j = 0; j < 4; j++) {
          float y2 = bf2f(y2p[((size_t)(n * 4096 + p0 + j)) * 256 + gcol]);
          ov[j] = acc[mi][ni][j] + bval + xv[j] + y2;
        }
        *(f32x4*)&((float*)outv)[oix] = ov;
        continue;
      }
#pragma unroll
      for (int j = 0; j < 4; j++) {
        int grow = rb + wr * 32 + mi * 16 + kg4 + j;
        float v = acc[mi][ni][j] + bval;
        if (EPI == 2) v = silu_f(v * s + tt);
        if (EPI == 3) v = v * s + tt;
        if (EPI == 4) v = silu_f(v);
        if (EPI == 1) {
          ((float*)outv)[(size_t)grow * Co + gcol] = v;
        } else if (EPI == 5) {
          if (gcol < 256)
            ((unsigned short*)outv)[(size_t)grow * 256 + gcol] = f2bf(v);
          else
            ((float*)e1)[(size_t)grow * 216 + (gcol - 256)] = v;
        } else {
          ((unsigned short*)outv)[(size_t)grow * Co + gcol] = f2bf(v);
        }
      }
    }
  }
}

// ---------------------------------------------------------------------------
// DCNv4 core body (two-phase), callable from fused kernel.
// ---------------------------------------------------------------------------
__device__ __forceinline__ void dcn_body(
    int bid, const unsigned short* __restrict__ value,
    const float* __restrict__ om, unsigned short* __restrict__ out,
    void* smemraw) {
  f32x4* wgt = (f32x4*)smemraw;
  i32x4* adr = (i32x4*)((char*)smemraw + 288 * 16);
  const int n = bid >> 10;
  const int p0 = (bid & 1023) * 4;
  const int t = threadIdx.x;

  for (int idx = t; idx < 288; idx += 256) {
    int pi = idx / 72;
    int gk = idx - pi * 72;
    int g = gk / 9, k = gk - g * 9;
    int p = p0 + pi;
    int h0 = p >> 6, w0 = p & 63;
    const float* omp = om + ((size_t)(n * 4096 + p)) * 216 + g * 27;
    float ox = omp[2 * k], oy = omp[2 * k + 1], mk = omp[18 + k];
    float px = (float)(w0 + (k % 3) - 1) + ox;
    float py = (float)(h0 + (k / 3) - 1) + oy;
    float x0f = floorf(px), y0f = floorf(py);
    float lx = px - x0f, ly = py - y0f;
    int x0 = (int)x0f, y0 = (int)y0f;
    int x1 = x0 + 1, y1 = y0 + 1;
    bool vx0 = (unsigned)x0 < 64u, vx1 = (unsigned)x1 < 64u;
    bool vy0 = (unsigned)y0 < 64u, vy1 = (unsigned)y1 < 64u;
    int cx0 = min(max(x0, 0), 63), cx1 = min(max(x1, 0), 63);
    int cy0 = min(max(y0, 0), 63), cy1 = min(max(y1, 0), 63);
    f32x4 w4;
    w4[0] = (1.f - ly) * (1.f - lx) * mk * (float)(vy0 && vx0);
    w4[1] = (1.f - ly) * lx * mk * (float)(vy0 && vx1);
    w4[2] = ly * (1.f - lx) * mk * (float)(vy1 && vx0);
    w4[3] = ly * lx * mk * (float)(vy1 && vx1);
    i32x4 a4;
    a4[0] = (cy0 * 64 + cx0) * 256;
    a4[1] = (cy0 * 64 + cx1) * 256;
    a4[2] = (cy1 * 64 + cx0) * 256;
    a4[3] = (cy1 * 64 + cx1) * 256;
    wgt[idx] = w4;
    adr[idx] = a4;
  }
  __syncthreads();

  const int pi = t >> 6;
  const int g = (t >> 3) & 7;
  const int l = t & 7;
  const int p = p0 + pi;
  const unsigned short* vb = value + ((size_t)n * 4096) * 256 + g * 32 + l * 4;
  const int bix = (pi * 8 + g) * 9;
  float a0 = 0.f, a1 = 0.f, a2 = 0.f, a3 = 0.f;
#pragma unroll
  for (int k = 0; k < 9; k++) {
    f32x4 wv = wgt[bix + k];
    i32x4 av = adr[bix + k];
    us4 q0 = *(const us4*)(vb + av[0]);
    us4 q1 = *(const us4*)(vb + av[1]);
    us4 q2 = *(const us4*)(vb + av[2]);
    us4 q3 = *(const us4*)(vb + av[3]);
    a0 += wv[0] * bf2f(q0[0]) + wv[1] * bf2f(q1[0]) + wv[2] * bf2f(q2[0]) + wv[3] * bf2f(q3[0]);
    a1 += wv[0] * bf2f(q0[1]) + wv[1] * bf2f(q1[1]) + wv[2] * bf2f(q2[1]) + wv[3] * bf2f(q3[1]);
    a2 += wv[0] * bf2f(q0[2]) + wv[1] * bf2f(q1[2]) + wv[2] * bf2f(q2[2]) + wv[3] * bf2f(q3[2]);
    a3 += wv[0] * bf2f(q0[3]) + wv[1] * bf2f(q1[3]) + wv[2] * bf2f(q2[3]) + wv[3] * bf2f(q3[3]);
  }
  us4 o;
  o[0] = f2bf(a0); o[1] = f2bf(a1); o[2] = f2bf(a2); o[3] = f2bf(a3);
  *(us4*)&out[((size_t)(n * 4096 + p)) * 256 + g * 32 + l * 4] = o;
}

// ---------------------------------------------------------------------------
// PREP: NCHW->tokens transpose (blocks 0..1023) + all weight conversions.
// ---------------------------------------------------------------------------
__global__ __launch_bounds__(256) void prep_k(
    const float* __restrict__ x, unsigned short* __restrict__ xt,
    const float* __restrict__ c1, unsigned short* __restrict__ o1,
    const float* __restrict__ c2, unsigned short* __restrict__ o2,
    const float* __restrict__ a0, unsigned short* __restrict__ b0,
    const float* __restrict__ a1, unsigned short* __restrict__ b1,
    const float* __restrict__ a2, unsigned short* __restrict__ b2,
    const float* __restrict__ a3, unsigned short* __restrict__ b3,
    const float* __restrict__ a4, unsigned short* __restrict__ b4,
    uint32* __restrict__ zp) {
  __shared__ float lds[64][65];
  int b = blockIdx.x;
  const int t = threadIdx.x;
  if (b == 0 && t < 32) zp[t] = 0u;
  if (b < 1024) {
    const int p0 = (b & 63) * 64, c0 = ((b >> 6) & 3) * 64, n = b >> 8;
    const int pp = t & 63, ccb = t >> 6;
    const float* xb = x + ((size_t)n * 256 + c0) * 4096 + p0;
#pragma unroll
    for (int i = 0; i < 16; i++) {
      int cc = ccb * 16 + i;
      lds[pp][cc] = xb[(size_t)cc * 4096 + pp];
    }
    __syncthreads();
#pragma unroll
    for (int i = 0; i < 2; i++) {
      int pp2 = (t >> 3) + i * 32;
      int c8 = (t & 7) * 8;
      us8 v;
#pragma unroll
      for (int j = 0; j < 8; j++) v[j] = f2bf(lds[pp2][c8 + j]);
      *(us8*)&xt[((size_t)(n * 4096 + p0 + pp2)) * 256 + c0 + c8] = v;
    }
    return;
  }
  int idx = (b - 1024) * 256 + t;
  if (idx < 294912) {
    int ci = idx & 255, r = idx >> 8;
    int tap = r % 9, co = r / 9;
    o1[idx] = f2bf(c1[((size_t)co * 256 + ci) * 9 + tap]);
    return;
  }
  idx -= 294912;
  if (idx < 294912) {
    int ci = idx & 127, r = idx >> 7;
    int tap = r % 9, co = r / 9;
    o2[idx] = f2bf(c2[((size_t)co * 128 + ci) * 9 + tap]);
    return;
  }
  idx -= 294912;
  const float* s;
  unsigned short* d;
  int off;
  if (idx < 65536)       { s = a0; d = b0; off = idx; }
  else if (idx < 120832) { s = a1; d = b1; off = idx - 65536; }
  else if (idx < 186368) { s = a2; d = b2; off = idx - 120832; }
  else if (idx < 382976) { s = a3; d = b3; off = idx - 186368; }
  else if (idx < 579584) { s = a4; d = b4; off = idx - 382976; }
  else return;
  d[off] = f2bf(s[off]);
}

// ---------------------------------------------------------------------------
// Stage 1: conv1 (blocks 0..511) ∪ fused val/om projection (512..2559).
// ---------------------------------------------------------------------------
__global__ __launch_bounds__(256) void fused_s1(
    const unsigned short* __restrict__ xt,
    const unsigned short* __restrict__ wc1, const float* __restrict__ g1,
    const float* __restrict__ bb1, const float* __restrict__ m1,
    const float* __restrict__ v1, unsigned short* __restrict__ y1t,
    const unsigned short* __restrict__ wval, const float* __restrict__ val_b,
    const float* __restrict__ om_b, float* __restrict__ omf,
    unsigned short* __restrict__ valt, const unsigned short* __restrict__ zpage) {
  __shared__ bf16x8 smem[2048];
  int b = blockIdx.x;
  if (b < 512) {
    gemm_body<2, 256>((b >> 1) * 64, (b & 1) * 64, xt, wc1, nullptr, 2304, 128,
                      y1t, g1, bb1, m1, v1, zpage, smem);
  } else {
    b -= 512;
    gemm_body<5, 0>((b >> 3) * 64, (b & 7) * 64, xt, wval, val_b, 256, 472,
                    valt, om_b, (const float*)omf, nullptr, nullptr, zpage, smem);
  }
}

// ---------------------------------------------------------------------------
// Stage 2: conv2 (blocks 0..1023) ∪ dcn core (1024..5119).
// ---------------------------------------------------------------------------
__global__ __launch_bounds__(256) void fused_s2(
    const unsigned short* __restrict__ y1t,
    const unsigned short* __restrict__ wc2, const float* __restrict__ g2,
    const float* __restrict__ bb2, const float* __restrict__ m2,
    const float* __restrict__ v2, unsigned short* __restrict__ y2t,
    const unsigned short* __restrict__ valt, const float* __restrict__ omf,
    unsigned short* __restrict__ dcnt, const unsigned short* __restrict__ zpage) {
  __shared__ bf16x8 smem[2048];
  int b = blockIdx.x;
  if (b < 1024) {
    gemm_body<2, 128>((b >> 2) * 64, (b & 3) * 64, y1t, wc2, nullptr, 1152, 256,
                      y2t, g2, bb2, m2, v2, zpage, smem);
  } else {
    dcn_body(b - 1024, valt, omf, dcnt, (void*)smem);
  }
}

// ---------------------------------------------------------------------------
// Standalone GEMM wrapper (outp / pw1 / pw2+output-fuse).
// ---------------------------------------------------------------------------
template <int EPI, int CIN>
__global__ __launch_bounds__(256) void gemm_k(
    const unsigned short* __restrict__ A, const unsigned short* __restrict__ Bw,
    const float* __restrict__ bias, int K, int Co, void* __restrict__ outv,
    const float* __restrict__ e0, const float* __restrict__ e1,
    const float* __restrict__ e2, const float* __restrict__ e3,
    const unsigned short* __restrict__ zpage) {
  __shared__ bf16x8 smem[2048];
  gemm_body<EPI, CIN>(blockIdx.y * 64, blockIdx.x * 64, A, Bw, bias, K, Co,
                      outv, e0, e1, e2, e3, zpage, smem);
}

// ---------------------------------------------------------------------------
extern "C" void kernel_launch(void* const* d_in, const int* in_sizes, int n_in,
                              void* d_out, int out_size, void* d_ws,
                              size_t ws_size, hipStream_t stream) {
  const float* x      = (const float*)d_in[0];
  const float* cv1_w  = (const float*)d_in[1];
  const float* cv1_g  = (const float*)d_in[2];
  const float* cv1_b  = (const float*)d_in[3];
  const float* cv1_m  = (const float*)d_in[4];
  const float* cv1_v  = (const float*)d_in[5];
  const float* cv2_w  = (const float*)d_in[6];
  const float* cv2_g  = (const float*)d_in[7];
  const float* cv2_b  = (const float*)d_in[8];
  const float* cv2_m  = (const float*)d_in[9];
  const float* cv2_v  = (const float*)d_in[10];
  const float* val_w  = (const float*)d_in[11];
  const float* val_b  = (const float*)d_in[12];
  const float* om_w   = (const float*)d_in[13];
  const float* om_b   = (const float*)d_in[14];
  const float* outp_w = (const float*)d_in[15];
  const float* outp_b = (const float*)d_in[16];
  const float* bn3_g  = (const float*)d_in[17];
  const float* bn3_b  = (const float*)d_in[18];
  const float* bn3_m  = (const float*)d_in[19];
  const float* bn3_v  = (const float*)d_in[20];
  const float* pw1_w  = (const float*)d_in[21];
  const float* pw1_b  = (const float*)d_in[22];
  const float* pw2_w  = (const float*)d_in[23];
  const float* pw2_b  = (const float*)d_in[24];
  float* out = (float*)d_out;

  char* w = (char*)d_ws;
  auto alloc = [&](size_t bytes) {
    char* p = w;
    w += (bytes + 255) & ~(size_t)255;
    return p;
  };
  unsigned short* xt    = (unsigned short*)alloc(16384ull * 256 * 2);
  unsigned short* y1t   = (unsigned short*)alloc(16384ull * 128 * 2);
  unsigned short* y2t   = (unsigned short*)alloc(16384ull * 256 * 2);
  unsigned short* valt  = (unsigned short*)alloc(16384ull * 256 * 2);
  float*          omf   = (float*)alloc(16384ull * 216 * 4);
  unsigned short* dcnt  = (unsigned short*)alloc(16384ull * 256 * 2);
  unsigned short* d1t   = (unsigned short*)alloc(16384ull * 256 * 2);
  unsigned short* p1t   = (unsigned short*)alloc(16384ull * 768 * 2);
  unsigned short* wc1   = (unsigned short*)alloc(128ull * 2304 * 2);
  unsigned short* wc2   = (unsigned short*)alloc(256ull * 1152 * 2);
  // wval and wom MUST be contiguous (fused val/om B-matrix, 472 x 256):
  unsigned short* wval  = (unsigned short*)alloc(256ull * 256 * 2);   // 256-mult
  unsigned short* wom   = (unsigned short*)alloc(216ull * 256 * 2);   // = wval + 65536
  unsigned short* woutp = (unsigned short*)alloc(256ull * 256 * 2);
  unsigned short* wpw1  = (unsigned short*)alloc(768ull * 256 * 2);
  unsigned short* wpw2  = (unsigned short*)alloc(256ull * 768 * 2);
  unsigned short* zpage = (unsigned short*)alloc(256);  // 64B zeros (+pad)

  // prep: tokens + weight conversions (1 launch)
  prep_k<<<5592, 256, 0, stream>>>(x, xt, cv1_w, wc1, cv2_w, wc2, val_w, wval,
                                   om_w, wom, outp_w, woutp, pw1_w, wpw1,
                                   pw2_w, wpw2, (uint32*)zpage);

  // stage 1: conv1 ∪ val/om projection
  fused_s1<<<2560, 256, 0, stream>>>(xt, wc1, cv1_g, cv1_b, cv1_m, cv1_v, y1t,
                                     wval, val_b, om_b, omf, valt, zpage);

  // stage 2: conv2 ∪ dcn core
  fused_s2<<<5120, 256, 0, stream>>>(y1t, wc2, cv2_g, cv2_b, cv2_m, cv2_v, y2t,
                                     valt, omf, dcnt, zpage);

  // tail chain
  gemm_k<3, 0><<<dim3(4, 256), 256, 0, stream>>>(
      dcnt, woutp, outp_b, 256, 256, d1t, bn3_g, bn3_b, bn3_m, bn3_v, zpage);
  gemm_k<4, 0><<<dim3(12, 256), 256, 0, stream>>>(
      d1t, wpw1, pw1_b, 256, 768, p1t, nullptr, nullptr, nullptr, nullptr, zpage);
  gemm_k<6, 0><<<dim3(4, 256), 256, 0, stream>>>(
      p1t, wpw2, pw2_b, 768, 256, out, x, (const float*)y2t, nullptr, nullptr, zpage);
}

// Round 8
// 186.685 us; speedup vs baseline: 1.1544x; 1.0319x over previous
//
#include <hip/hip_runtime.h>
#include <math.h>

typedef __attribute__((ext_vector_type(8))) __bf16 bf16x8;
typedef __attribute__((ext_vector_type(8))) unsigned short us8;
typedef __attribute__((ext_vector_type(4))) unsigned short us4;
typedef __attribute__((ext_vector_type(4))) float f32x4;
typedef __attribute__((ext_vector_type(4))) int i32x4;
typedef unsigned int uint32;

#define EPSV 1e-5f

__device__ __forceinline__ float silu_f(float v) { return v / (1.f + __expf(-v)); }

__device__ __forceinline__ unsigned short f2bf(float f) {
  uint32 u = __builtin_bit_cast(uint32, f);
  u += 0x7fffu + ((u >> 16) & 1u);   // RNE
  return (unsigned short)(u >> 16);
}
__device__ __forceinline__ float bf2f(unsigned short h) {
  uint32 u = ((uint32)h) << 16;
  return __builtin_bit_cast(float, u);
}

// async global->LDS DMA, 16B per lane. LDS dest = wave-uniform base + lane*16.
__device__ __forceinline__ void gl_lds16(const void* g, void* l) {
  __builtin_amdgcn_global_load_lds(
      (const __attribute__((address_space(1))) unsigned int*)g,
      (__attribute__((address_space(3))) unsigned int*)l, 16, 0, 0);
}

// ---------------------------------------------------------------------------
// GEMM body, m97 geometry: 128x128 tile, 4 waves (each 64x64 = 4x4 frags of
// 16x16x32 -> 16 MFMA/iter/wave), BK=32, double-buffered 32 KB LDS staged by
// global_load_lds.  Chunk c (0..511 per matrix): row16=c&15, kg=(c>>4)&3,
// msub=c>>6; LDS chunk id == c (identity), frag read lane-linear.
// EPI: 0 bias->bf16 | 1 bias->f32 | 2 BN+SiLU->bf16 | 3 bias+BN->bf16
//      4 bias+SiLU->bf16 | 5 split val/om | 6 bias + x + y2 -> NCHW f32
// ---------------------------------------------------------------------------
template <int EPI, int CIN>
__device__ __forceinline__ void gemm_body(
    int rb, int cb,
    const unsigned short* __restrict__ A, const unsigned short* __restrict__ Bw,
    const float* __restrict__ bias, int K, int Co, void* __restrict__ outv,
    const float* __restrict__ e0, const float* __restrict__ e1,
    const float* __restrict__ e2, const float* __restrict__ e3,
    const unsigned short* __restrict__ zpage, bf16x8* smem) {
  const int t = threadIdx.x;
  const int lane = t & 63;
  const int wv = t >> 6;
  const int wr = wv >> 1, wc = wv & 1;

  f32x4 acc[4][4];
#pragma unroll
  for (int i = 0; i < 4; i++)
#pragma unroll
    for (int j = 0; j < 4; j++) acc[i][j] = (f32x4){0.f, 0.f, 0.f, 0.f};

  // ---- hoisted per-chunk addressing (2 chunks each for A and B)
  const unsigned short* Abase[2];
  int aprow[2], apcol[2], akoff[2];
  const unsigned short* Bbase[2];
#pragma unroll
  for (int i = 0; i < 2; i++) {
    int c = t + 256 * i;
    int row16 = c & 15, kg = (c >> 4) & 3, msub = c >> 6;  // msub 0..7
    int row = msub * 16 + row16;                            // 0..127
    int koff = kg * 8;                                      // 0..24
    akoff[i] = koff;
    int grow = rb + row;
    if constexpr (CIN > 0) {
      int n = grow >> 12, p = grow & 4095;
      aprow[i] = p >> 6;
      apcol[i] = p & 63;
      Abase[i] = A + (size_t)n * 4096 * CIN;
    } else {
      Abase[i] = A + (size_t)grow * K + koff;
    }
    int col = cb + row;  // same row16/msub decomposition for B columns
    Bbase[i] = (col < Co) ? (Bw + (size_t)col * K + koff) : zpage;
  }
  auto addrA = [&](int i, int kb) -> const unsigned short* {
    if constexpr (CIN > 0) {
      int tap = kb / CIN;
      int ci = (kb & (CIN - 1)) + akoff[i];
      int dy = tap / 3 - 1, dx = tap % 3 - 1;
      int h = aprow[i] + dy, w = apcol[i] + dx;
      if (((unsigned)h < 64u) & ((unsigned)w < 64u))
        return &Abase[i][(size_t)(h * 64 + w) * CIN + ci];
      return zpage;
    } else {
      return Abase[i] + kb;
    }
  };
  auto addrB = [&](int i, int kb) -> const unsigned short* {
    return (Bbase[i] == zpage) ? zpage : Bbase[i] + kb;
  };
  auto stage = [&](int buf, int kb) {
    bf16x8* base = &smem[buf * 1024];
    gl_lds16(addrA(0, kb), (void*)&base[t]);
    gl_lds16(addrA(1, kb), (void*)&base[t + 256]);
    gl_lds16(addrB(0, kb), (void*)&base[512 + t]);
    gl_lds16(addrB(1, kb), (void*)&base[512 + t + 256]);
  };

  const int nt = K >> 5;
  stage(0, 0);
  __syncthreads();
  int cur = 0;
  for (int it = 0; it < nt; ++it) {
    if (it + 1 < nt) stage(cur ^ 1, (it + 1) << 5);
    const bf16x8* Ab = &smem[cur * 1024];
    const bf16x8* Bb = Ab + 512;
    bf16x8 af[4], bfr[4];
#pragma unroll
    for (int mi = 0; mi < 4; mi++) af[mi] = Ab[(wr * 4 + mi) * 64 + lane];
#pragma unroll
    for (int ni = 0; ni < 4; ni++) bfr[ni] = Bb[(wc * 4 + ni) * 64 + lane];
    __builtin_amdgcn_s_setprio(1);
#pragma unroll
    for (int mi = 0; mi < 4; mi++)
#pragma unroll
      for (int ni = 0; ni < 4; ni++)
        acc[mi][ni] = __builtin_amdgcn_mfma_f32_16x16x32_bf16(af[mi], bfr[ni],
                                                              acc[mi][ni], 0, 0, 0);
    __builtin_amdgcn_s_setprio(0);
    __syncthreads();
    cur ^= 1;
  }

  // ---- epilogue.  C/D: col = lane&15, row = (lane>>4)*4 + reg
  const int lr = lane & 15, kg4 = (lane >> 4) * 4;
#pragma unroll
  for (int mi = 0; mi < 4; mi++) {
#pragma unroll
    for (int ni = 0; ni < 4; ni++) {
      int gcol = cb + wc * 64 + ni * 16 + lr;
      if (gcol >= Co) continue;
      float bval, s = 1.f, tt = 0.f;
      if (EPI == 2) bval = 0.f;
      else if (EPI == 5) bval = (gcol < 256) ? bias[gcol] : e0[gcol - 256];
      else bval = bias[gcol];
      if (EPI == 2 || EPI == 3) {
        s = e0[gcol] * rsqrtf(e3[gcol] + EPSV);
        tt = e1[gcol] - e2[gcol] * s;
      }
      if (EPI == 6) {
        int grow0 = rb + wr * 64 + mi * 16 + kg4;
        int n = grow0 >> 12, p0 = grow0 & 4095;
        size_t oix = ((size_t)(n * 256 + gcol)) * 4096 + p0;
        f32x4 xv = *(const f32x4*)&((const float*)e0)[oix];
        const unsigned short* y2p = (const unsigned short*)e1;
        f32x4 ov;
#pragma unroll
        for (int j = 0; j < 4; j++) {
          float y2 = bf2f(y2p[((size_t)(n * 4096 + p0 + j)) * 256 + gcol]);
          ov[j] = acc[mi][ni][j] + bval + xv[j] + y2;
        }
        *(f32x4*)&((float*)outv)[oix] = ov;
        continue;
      }
#pragma unroll
      for (int j = 0; j < 4; j++) {
        int grow = rb + wr * 64 + mi * 16 + kg4 + j;
        float v = acc[mi][ni][j] + bval;
        if (EPI == 2) v = silu_f(v * s + tt);
        if (EPI == 3) v = v * s + tt;
        if (EPI == 4) v = silu_f(v);
        if (EPI == 1) {
          ((float*)outv)[(size_t)grow * Co + gcol] = v;
        } else if (EPI == 5) {
          if (gcol < 256)
            ((unsigned short*)outv)[(size_t)grow * 256 + gcol] = f2bf(v);
          else
            ((float*)e1)[(size_t)grow * 216 + (gcol - 256)] = v;
        } else {
          ((unsigned short*)outv)[(size_t)grow * Co + gcol] = f2bf(v);
        }
      }
    }
  }
}

// ---------------------------------------------------------------------------
// DCNv4 core body (two-phase), callable from fused kernel.
// ---------------------------------------------------------------------------
__device__ __forceinline__ void dcn_body(
    int bid, const unsigned short* __restrict__ value,
    const float* __restrict__ om, unsigned short* __restrict__ out,
    void* smemraw) {
  f32x4* wgt = (f32x4*)smemraw;
  i32x4* adr = (i32x4*)((char*)smemraw + 288 * 16);
  const int n = bid >> 10;
  const int p0 = (bid & 1023) * 4;
  const int t = threadIdx.x;

  for (int idx = t; idx < 288; idx += 256) {
    int pi = idx / 72;
    int gk = idx - pi * 72;
    int g = gk / 9, k = gk - g * 9;
    int p = p0 + pi;
    int h0 = p >> 6, w0 = p & 63;
    const float* omp = om + ((size_t)(n * 4096 + p)) * 216 + g * 27;
    float ox = omp[2 * k], oy = omp[2 * k + 1], mk = omp[18 + k];
    float px = (float)(w0 + (k % 3) - 1) + ox;
    float py = (float)(h0 + (k / 3) - 1) + oy;
    float x0f = floorf(px), y0f = floorf(py);
    float lx = px - x0f, ly = py - y0f;
    int x0 = (int)x0f, y0 = (int)y0f;
    int x1 = x0 + 1, y1 = y0 + 1;
    bool vx0 = (unsigned)x0 < 64u, vx1 = (unsigned)x1 < 64u;
    bool vy0 = (unsigned)y0 < 64u, vy1 = (unsigned)y1 < 64u;
    int cx0 = min(max(x0, 0), 63), cx1 = min(max(x1, 0), 63);
    int cy0 = min(max(y0, 0), 63), cy1 = min(max(y1, 0), 63);
    f32x4 w4;
    w4[0] = (1.f - ly) * (1.f - lx) * mk * (float)(vy0 && vx0);
    w4[1] = (1.f - ly) * lx * mk * (float)(vy0 && vx1);
    w4[2] = ly * (1.f - lx) * mk * (float)(vy1 && vx0);
    w4[3] = ly * lx * mk * (float)(vy1 && vx1);
    i32x4 a4;
    a4[0] = (cy0 * 64 + cx0) * 256;
    a4[1] = (cy0 * 64 + cx1) * 256;
    a4[2] = (cy1 * 64 + cx0) * 256;
    a4[3] = (cy1 * 64 + cx1) * 256;
    wgt[idx] = w4;
    adr[idx] = a4;
  }
  __syncthreads();

  const int pi = t >> 6;
  const int g = (t >> 3) & 7;
  const int l = t & 7;
  const int p = p0 + pi;
  const unsigned short* vb = value + ((size_t)n * 4096) * 256 + g * 32 + l * 4;
  const int bix = (pi * 8 + g) * 9;
  float a0 = 0.f, a1 = 0.f, a2 = 0.f, a3 = 0.f;
#pragma unroll
  for (int k = 0; k < 9; k++) {
    f32x4 wv = wgt[bix + k];
    i32x4 av = adr[bix + k];
    us4 q0 = *(const us4*)(vb + av[0]);
    us4 q1 = *(const us4*)(vb + av[1]);
    us4 q2 = *(const us4*)(vb + av[2]);
    us4 q3 = *(const us4*)(vb + av[3]);
    a0 += wv[0] * bf2f(q0[0]) + wv[1] * bf2f(q1[0]) + wv[2] * bf2f(q2[0]) + wv[3] * bf2f(q3[0]);
    a1 += wv[0] * bf2f(q0[1]) + wv[1] * bf2f(q1[1]) + wv[2] * bf2f(q2[1]) + wv[3] * bf2f(q3[1]);
    a2 += wv[0] * bf2f(q0[2]) + wv[1] * bf2f(q1[2]) + wv[2] * bf2f(q2[2]) + wv[3] * bf2f(q3[2]);
    a3 += wv[0] * bf2f(q0[3]) + wv[1] * bf2f(q1[3]) + wv[2] * bf2f(q2[3]) + wv[3] * bf2f(q3[3]);
  }
  us4 o;
  o[0] = f2bf(a0); o[1] = f2bf(a1); o[2] = f2bf(a2); o[3] = f2bf(a3);
  *(us4*)&out[((size_t)(n * 4096 + p)) * 256 + g * 32 + l * 4] = o;
}

// ---------------------------------------------------------------------------
// PREP: NCHW->tokens transpose (blocks 0..1023) + all weight conversions.
// ---------------------------------------------------------------------------
__global__ __launch_bounds__(256) void prep_k(
    const float* __restrict__ x, unsigned short* __restrict__ xt,
    const float* __restrict__ c1, unsigned short* __restrict__ o1,
    const float* __restrict__ c2, unsigned short* __restrict__ o2,
    const float* __restrict__ a0, unsigned short* __restrict__ b0,
    const float* __restrict__ a1, unsigned short* __restrict__ b1,
    const float* __restrict__ a2, unsigned short* __restrict__ b2,
    const float* __restrict__ a3, unsigned short* __restrict__ b3,
    const float* __restrict__ a4, unsigned short* __restrict__ b4,
    uint32* __restrict__ zp) {
  __shared__ float lds[64][65];
  int b = blockIdx.x;
  const int t = threadIdx.x;
  if (b == 0 && t < 32) zp[t] = 0u;
  if (b < 1024) {
    const int p0 = (b & 63) * 64, c0 = ((b >> 6) & 3) * 64, n = b >> 8;
    const int pp = t & 63, ccb = t >> 6;
    const float* xb = x + ((size_t)n * 256 + c0) * 4096 + p0;
#pragma unroll
    for (int i = 0; i < 16; i++) {
      int cc = ccb * 16 + i;
      lds[pp][cc] = xb[(size_t)cc * 4096 + pp];
    }
    __syncthreads();
#pragma unroll
    for (int i = 0; i < 2; i++) {
      int pp2 = (t >> 3) + i * 32;
      int c8 = (t & 7) * 8;
      us8 v;
#pragma unroll
      for (int j = 0; j < 8; j++) v[j] = f2bf(lds[pp2][c8 + j]);
      *(us8*)&xt[((size_t)(n * 4096 + p0 + pp2)) * 256 + c0 + c8] = v;
    }
    return;
  }
  int idx = (b - 1024) * 256 + t;
  if (idx < 294912) {
    int ci = idx & 255, r = idx >> 8;
    int tap = r % 9, co = r / 9;
    o1[idx] = f2bf(c1[((size_t)co * 256 + ci) * 9 + tap]);
    return;
  }
  idx -= 294912;
  if (idx < 294912) {
    int ci = idx & 127, r = idx >> 7;
    int tap = r % 9, co = r / 9;
    o2[idx] = f2bf(c2[((size_t)co * 128 + ci) * 9 + tap]);
    return;
  }
  idx -= 294912;
  const float* s;
  unsigned short* d;
  int off;
  if (idx < 65536)       { s = a0; d = b0; off = idx; }
  else if (idx < 120832) { s = a1; d = b1; off = idx - 65536; }
  else if (idx < 186368) { s = a2; d = b2; off = idx - 120832; }
  else if (idx < 382976) { s = a3; d = b3; off = idx - 186368; }
  else if (idx < 579584) { s = a4; d = b4; off = idx - 382976; }
  else return;
  d[off] = f2bf(s[off]);
}

// ---------------------------------------------------------------------------
// Stage 1: conv1 (blocks 0..127) ∪ fused val/om projection (128..639).
// ---------------------------------------------------------------------------
__global__ __launch_bounds__(256) void fused_s1(
    const unsigned short* __restrict__ xt,
    const unsigned short* __restrict__ wc1, const float* __restrict__ g1,
    const float* __restrict__ bb1, const float* __restrict__ m1,
    const float* __restrict__ v1, unsigned short* __restrict__ y1t,
    const unsigned short* __restrict__ wval, const float* __restrict__ val_b,
    const float* __restrict__ om_b, float* __restrict__ omf,
    unsigned short* __restrict__ valt, const unsigned short* __restrict__ zpage) {
  __shared__ bf16x8 smem[2048];
  int b = blockIdx.x;
  if (b < 128) {
    gemm_body<2, 256>(b * 128, 0, xt, wc1, nullptr, 2304, 128,
                      y1t, g1, bb1, m1, v1, zpage, smem);
  } else {
    b -= 128;
    gemm_body<5, 0>((b >> 2) * 128, (b & 3) * 128, xt, wval, val_b, 256, 472,
                    valt, om_b, (const float*)omf, nullptr, nullptr, zpage, smem);
  }
}

// ---------------------------------------------------------------------------
// Stage 2: conv2 (blocks 0..255) ∪ dcn core (256..4351).
// ---------------------------------------------------------------------------
__global__ __launch_bounds__(256) void fused_s2(
    const unsigned short* __restrict__ y1t,
    const unsigned short* __restrict__ wc2, const float* __restrict__ g2,
    const float* __restrict__ bb2, const float* __restrict__ m2,
    const float* __restrict__ v2, unsigned short* __restrict__ y2t,
    const unsigned short* __restrict__ valt, const float* __restrict__ omf,
    unsigned short* __restrict__ dcnt, const unsigned short* __restrict__ zpage) {
  __shared__ bf16x8 smem[2048];
  int b = blockIdx.x;
  if (b < 256) {
    gemm_body<2, 128>((b >> 1) * 128, (b & 1) * 128, y1t, wc2, nullptr, 1152, 256,
                      y2t, g2, bb2, m2, v2, zpage, smem);
  } else {
    dcn_body(b - 256, valt, omf, dcnt, (void*)smem);
  }
}

// ---------------------------------------------------------------------------
// Standalone GEMM wrapper (outp / pw1 / pw2+output-fuse).
// ---------------------------------------------------------------------------
template <int EPI, int CIN>
__global__ __launch_bounds__(256) void gemm_k(
    const unsigned short* __restrict__ A, const unsigned short* __restrict__ Bw,
    const float* __restrict__ bias, int K, int Co, void* __restrict__ outv,
    const float* __restrict__ e0, const float* __restrict__ e1,
    const float* __restrict__ e2, const float* __restrict__ e3,
    const unsigned short* __restrict__ zpage) {
  __shared__ bf16x8 smem[2048];
  gemm_body<EPI, CIN>(blockIdx.y * 128, blockIdx.x * 128, A, Bw, bias, K, Co,
                      outv, e0, e1, e2, e3, zpage, smem);
}

// ---------------------------------------------------------------------------
extern "C" void kernel_launch(void* const* d_in, const int* in_sizes, int n_in,
                              void* d_out, int out_size, void* d_ws,
                              size_t ws_size, hipStream_t stream) {
  const float* x      = (const float*)d_in[0];
  const float* cv1_w  = (const float*)d_in[1];
  const float* cv1_g  = (const float*)d_in[2];
  const float* cv1_b  = (const float*)d_in[3];
  const float* cv1_m  = (const float*)d_in[4];
  const float* cv1_v  = (const float*)d_in[5];
  const float* cv2_w  = (const float*)d_in[6];
  const float* cv2_g  = (const float*)d_in[7];
  const float* cv2_b  = (const float*)d_in[8];
  const float* cv2_m  = (const float*)d_in[9];
  const float* cv2_v  = (const float*)d_in[10];
  const float* val_w  = (const float*)d_in[11];
  const float* val_b  = (const float*)d_in[12];
  const float* om_w   = (const float*)d_in[13];
  const float* om_b   = (const float*)d_in[14];
  const float* outp_w = (const float*)d_in[15];
  const float* outp_b = (const float*)d_in[16];
  const float* bn3_g  = (const float*)d_in[17];
  const float* bn3_b  = (const float*)d_in[18];
  const float* bn3_m  = (const float*)d_in[19];
  const float* bn3_v  = (const float*)d_in[20];
  const float* pw1_w  = (const float*)d_in[21];
  const float* pw1_b  = (const float*)d_in[22];
  const float* pw2_w  = (const float*)d_in[23];
  const float* pw2_b  = (const float*)d_in[24];
  float* out = (float*)d_out;

  char* w = (char*)d_ws;
  auto alloc = [&](size_t bytes) {
    char* p = w;
    w += (bytes + 255) & ~(size_t)255;
    return p;
  };
  unsigned short* xt    = (unsigned short*)alloc(16384ull * 256 * 2);
  unsigned short* y1t   = (unsigned short*)alloc(16384ull * 128 * 2);
  unsigned short* y2t   = (unsigned short*)alloc(16384ull * 256 * 2);
  unsigned short* valt  = (unsigned short*)alloc(16384ull * 256 * 2);
  float*          omf   = (float*)alloc(16384ull * 216 * 4);
  unsigned short* dcnt  = (unsigned short*)alloc(16384ull * 256 * 2);
  unsigned short* d1t   = (unsigned short*)alloc(16384ull * 256 * 2);
  unsigned short* p1t   = (unsigned short*)alloc(16384ull * 768 * 2);
  unsigned short* wc1   = (unsigned short*)alloc(128ull * 2304 * 2);
  unsigned short* wc2   = (unsigned short*)alloc(256ull * 1152 * 2);
  // wval and wom MUST be contiguous (fused val/om B-matrix, 472 x 256):
  unsigned short* wval  = (unsigned short*)alloc(256ull * 256 * 2);   // 256-mult
  unsigned short* wom   = (unsigned short*)alloc(216ull * 256 * 2);   // = wval + 65536
  unsigned short* woutp = (unsigned short*)alloc(256ull * 256 * 2);
  unsigned short* wpw1  = (unsigned short*)alloc(768ull * 256 * 2);
  unsigned short* wpw2  = (unsigned short*)alloc(256ull * 768 * 2);
  unsigned short* zpage = (unsigned short*)alloc(256);  // 64B zeros (+pad)

  // prep: tokens + weight conversions (1 launch)
  prep_k<<<5592, 256, 0, stream>>>(x, xt, cv1_w, wc1, cv2_w, wc2, val_w, wval,
                                   om_w, wom, outp_w, woutp, pw1_w, wpw1,
                                   pw2_w, wpw2, (uint32*)zpage);

  // stage 1: conv1 ∪ val/om projection
  fused_s1<<<640, 256, 0, stream>>>(xt, wc1, cv1_g, cv1_b, cv1_m, cv1_v, y1t,
                                    wval, val_b, om_b, omf, valt, zpage);

  // stage 2: conv2 ∪ dcn core
  fused_s2<<<4352, 256, 0, stream>>>(y1t, wc2, cv2_g, cv2_b, cv2_m, cv2_v, y2t,
                                     valt, omf, dcnt, zpage);

  // tail chain
  gemm_k<3, 0><<<dim3(2, 128), 256, 0, stream>>>(
      dcnt, woutp, outp_b, 256, 256, d1t, bn3_g, bn3_b, bn3_m, bn3_v, zpage);
  gemm_k<4, 0><<<dim3(6, 128), 256, 0, stream>>>(
      d1t, wpw1, pw1_b, 256, 768, p1t, nullptr, nullptr, nullptr, nullptr, zpage);
  gemm_k<6, 0><<<dim3(2, 128), 256, 0, stream>>>(
      p1t, wpw2, pw2_b, 768, 256, out, x, (const float*)y2t, nullptr, nullptr, zpage);
}

// Round 9
// 164.714 us; speedup vs baseline: 1.3084x; 1.1334x over previous
//
#include <hip/hip_runtime.h>
#include <math.h>

typedef __attribute__((ext_vector_type(8))) __bf16 bf16x8;
typedef __attribute__((ext_vector_type(8))) unsigned short us8;
typedef __attribute__((ext_vector_type(4))) unsigned short us4;
typedef __attribute__((ext_vector_type(4))) float f32x4;
typedef __attribute__((ext_vector_type(4))) int i32x4;
typedef unsigned int uint32;

#define EPSV 1e-5f

__device__ __forceinline__ float silu_f(float v) { return v / (1.f + __expf(-v)); }

__device__ __forceinline__ unsigned short f2bf(float f) {
  uint32 u = __builtin_bit_cast(uint32, f);
  u += 0x7fffu + ((u >> 16) & 1u);   // RNE
  return (unsigned short)(u >> 16);
}
__device__ __forceinline__ float bf2f(unsigned short h) {
  uint32 u = ((uint32)h) << 16;
  return __builtin_bit_cast(float, u);
}

// async global->LDS DMA, 16B per lane. LDS dest = wave-uniform base + lane*16.
__device__ __forceinline__ void gl_lds16(const void* g, void* l) {
  __builtin_amdgcn_global_load_lds(
      (const __attribute__((address_space(1))) unsigned int*)g,
      (__attribute__((address_space(3))) unsigned int*)l, 16, 0, 0);
}

// ---------------------------------------------------------------------------
// GEMM body.  BM=128 fixed; BN in {128, 64}.  4 waves:
//   BN=128: wave tile 64x64 (4x4 frags, 16 MFMA/iter)
//   BN=64 : wave tile 64x32 (4x2 frags,  8 MFMA/iter)
// BK=32, double-buffered LDS via global_load_lds.  Chunk c: row16=c&15,
// kg=(c>>4)&3, sub=c>>6 -> row=sub*16+row16, koff=kg*8; identity LDS id.
// k0/KL support split-K (absolute kb = k0 + it*32; conv tap = kb/CIN).
// EPI: 0 bias->bf16 | 2 BN+SiLU->bf16 | 3 bias+BN->bf16 | 4 bias+SiLU->bf16
//      5 split val/om | 6 bias + x + y2 -> NCHW f32 | 7 raw f32 partial
// ---------------------------------------------------------------------------
template <int EPI, int CIN, int BN>
__device__ __forceinline__ void gemm_body(
    int rb, int cb, int k0, int KL,
    const unsigned short* __restrict__ A, const unsigned short* __restrict__ Bw,
    const float* __restrict__ bias, int K, int Co, void* __restrict__ outv,
    const float* __restrict__ e0, const float* __restrict__ e1,
    const float* __restrict__ e2, const float* __restrict__ e3,
    const unsigned short* __restrict__ zpage, bf16x8* smem) {
  constexpr int NFR = BN / 32;        // N-frags per wave (4 or 2)
  constexpr int NB = BN / 64;         // B chunks per thread (2 or 1)
  constexpr int CPB = 512 + BN * 4;   // chunks per LDS buffer (1024 or 768)
  const int t = threadIdx.x;
  const int lane = t & 63;
  const int wv = t >> 6;
  const int wr = wv >> 1, wc = wv & 1;

  f32x4 acc[4][NFR];
#pragma unroll
  for (int i = 0; i < 4; i++)
#pragma unroll
    for (int j = 0; j < NFR; j++) acc[i][j] = (f32x4){0.f, 0.f, 0.f, 0.f};

  // ---- hoisted addressing
  const unsigned short* Abase[2];
  int aprow[2], apcol[2], akoff[2];
#pragma unroll
  for (int i = 0; i < 2; i++) {
    int c = t + 256 * i;
    int row = (c >> 6) * 16 + (c & 15);
    int koff = ((c >> 4) & 3) * 8;
    akoff[i] = koff;
    int grow = rb + row;
    if constexpr (CIN > 0) {
      int n = grow >> 12, p = grow & 4095;
      aprow[i] = p >> 6;
      apcol[i] = p & 63;
      Abase[i] = A + (size_t)n * 4096 * CIN;
    } else {
      Abase[i] = A + (size_t)grow * K + koff;
    }
  }
  const unsigned short* Bbase[NB];
#pragma unroll
  for (int i = 0; i < NB; i++) {
    int c = t + 256 * i;
    int col = cb + (c >> 6) * 16 + (c & 15);
    int koff = ((c >> 4) & 3) * 8;
    Bbase[i] = (col < Co) ? (Bw + (size_t)col * K + koff) : zpage;
  }
  auto addrA = [&](int i, int kb) -> const unsigned short* {
    if constexpr (CIN > 0) {
      int tap = kb / CIN;
      int ci = (kb & (CIN - 1)) + akoff[i];
      int dy = tap / 3 - 1, dx = tap % 3 - 1;
      int h = aprow[i] + dy, w = apcol[i] + dx;
      if (((unsigned)h < 64u) & ((unsigned)w < 64u))
        return &Abase[i][(size_t)(h * 64 + w) * CIN + ci];
      return zpage;
    } else {
      return Abase[i] + kb;
    }
  };
  auto stage = [&](int buf, int kb) {
    bf16x8* base = &smem[buf * CPB];
    gl_lds16(addrA(0, kb), (void*)&base[t]);
    gl_lds16(addrA(1, kb), (void*)&base[t + 256]);
    gl_lds16((Bbase[0] == zpage) ? zpage : Bbase[0] + kb, (void*)&base[512 + t]);
    if constexpr (NB == 2)
      gl_lds16((Bbase[1] == zpage) ? zpage : Bbase[1] + kb,
               (void*)&base[512 + t + 256]);
  };

  const int nt = KL >> 5;
  stage(0, k0);
  __syncthreads();
  int cur = 0;
  for (int it = 0; it < nt; ++it) {
    if (it + 1 < nt) stage(cur ^ 1, k0 + ((it + 1) << 5));
    const bf16x8* Ab = &smem[cur * CPB];
    const bf16x8* Bb = Ab + 512;
    bf16x8 af[4], bfr[NFR];
#pragma unroll
    for (int mi = 0; mi < 4; mi++) af[mi] = Ab[(wr * 4 + mi) * 64 + lane];
#pragma unroll
    for (int ni = 0; ni < NFR; ni++) bfr[ni] = Bb[(wc * NFR + ni) * 64 + lane];
    __builtin_amdgcn_s_setprio(1);
#pragma unroll
    for (int mi = 0; mi < 4; mi++)
#pragma unroll
      for (int ni = 0; ni < NFR; ni++)
        acc[mi][ni] = __builtin_amdgcn_mfma_f32_16x16x32_bf16(af[mi], bfr[ni],
                                                              acc[mi][ni], 0, 0, 0);
    __builtin_amdgcn_s_setprio(0);
    __syncthreads();
    cur ^= 1;
  }

  // ---- epilogue.  C/D: col = lane&15, row = (lane>>4)*4 + reg
  const int lr = lane & 15, kg4 = (lane >> 4) * 4;
#pragma unroll
  for (int mi = 0; mi < 4; mi++) {
#pragma unroll
    for (int ni = 0; ni < NFR; ni++) {
      int gcol = cb + wc * (BN / 2) + ni * 16 + lr;
      if (gcol >= Co) continue;
      float bval, s = 1.f, tt = 0.f;
      if (EPI == 2 || EPI == 7) bval = 0.f;
      else if (EPI == 5) bval = (gcol < 256) ? bias[gcol] : e0[gcol - 256];
      else bval = bias[gcol];
      if (EPI == 2 || EPI == 3) {
        s = e0[gcol] * rsqrtf(e3[gcol] + EPSV);
        tt = e1[gcol] - e2[gcol] * s;
      }
      if (EPI == 6) {
        int grow0 = rb + wr * 64 + mi * 16 + kg4;
        int n = grow0 >> 12, p0 = grow0 & 4095;
        size_t oix = ((size_t)(n * 256 + gcol)) * 4096 + p0;
        f32x4 xv = *(const f32x4*)&((const float*)e0)[oix];
        const unsigned short* y2p = (const unsigned short*)e1;
        f32x4 ov;
#pragma unroll
        for (int j = 0; j < 4; j++) {
          float y2 = bf2f(y2p[((size_t)(n * 4096 + p0 + j)) * 256 + gcol]);
          ov[j] = acc[mi][ni][j] + bval + xv[j] + y2;
        }
        *(f32x4*)&((float*)outv)[oix] = ov;
        continue;
      }
#pragma unroll
      for (int j = 0; j < 4; j++) {
        int grow = rb + wr * 64 + mi * 16 + kg4 + j;
        float v = acc[mi][ni][j] + bval;
        if (EPI == 2) v = silu_f(v * s + tt);
        if (EPI == 3) v = v * s + tt;
        if (EPI == 4) v = silu_f(v);
        if (EPI == 7) {
          ((float*)outv)[(size_t)grow * Co + gcol] = v;
        } else if (EPI == 5) {
          if (gcol < 256)
            ((unsigned short*)outv)[(size_t)grow * 256 + gcol] = f2bf(v);
          else
            ((float*)e1)[(size_t)grow * 216 + (gcol - 256)] = v;
        } else {
          ((unsigned short*)outv)[(size_t)grow * Co + gcol] = f2bf(v);
        }
      }
    }
  }
}

// ---------------------------------------------------------------------------
// DCNv4 core body (two-phase).
// ---------------------------------------------------------------------------
__device__ __forceinline__ void dcn_body(
    int bid, const unsigned short* __restrict__ value,
    const float* __restrict__ om, unsigned short* __restrict__ out,
    void* smemraw) {
  f32x4* wgt = (f32x4*)smemraw;
  i32x4* adr = (i32x4*)((char*)smemraw + 288 * 16);
  const int n = bid >> 10;
  const int p0 = (bid & 1023) * 4;
  const int t = threadIdx.x;

  for (int idx = t; idx < 288; idx += 256) {
    int pi = idx / 72;
    int gk = idx - pi * 72;
    int g = gk / 9, k = gk - g * 9;
    int p = p0 + pi;
    int h0 = p >> 6, w0 = p & 63;
    const float* omp = om + ((size_t)(n * 4096 + p)) * 216 + g * 27;
    float ox = omp[2 * k], oy = omp[2 * k + 1], mk = omp[18 + k];
    float px = (float)(w0 + (k % 3) - 1) + ox;
    float py = (float)(h0 + (k / 3) - 1) + oy;
    float x0f = floorf(px), y0f = floorf(py);
    float lx = px - x0f, ly = py - y0f;
    int x0 = (int)x0f, y0 = (int)y0f;
    int x1 = x0 + 1, y1 = y0 + 1;
    bool vx0 = (unsigned)x0 < 64u, vx1 = (unsigned)x1 < 64u;
    bool vy0 = (unsigned)y0 < 64u, vy1 = (unsigned)y1 < 64u;
    int cx0 = min(max(x0, 0), 63), cx1 = min(max(x1, 0), 63);
    int cy0 = min(max(y0, 0), 63), cy1 = min(max(y1, 0), 63);
    f32x4 w4;
    w4[0] = (1.f - ly) * (1.f - lx) * mk * (float)(vy0 && vx0);
    w4[1] = (1.f - ly) * lx * mk * (float)(vy0 && vx1);
    w4[2] = ly * (1.f - lx) * mk * (float)(vy1 && vx0);
    w4[3] = ly * lx * mk * (float)(vy1 && vx1);
    i32x4 a4;
    a4[0] = (cy0 * 64 + cx0) * 256;
    a4[1] = (cy0 * 64 + cx1) * 256;
    a4[2] = (cy1 * 64 + cx0) * 256;
    a4[3] = (cy1 * 64 + cx1) * 256;
    wgt[idx] = w4;
    adr[idx] = a4;
  }
  __syncthreads();

  const int pi = t >> 6;
  const int g = (t >> 3) & 7;
  const int l = t & 7;
  const int p = p0 + pi;
  const unsigned short* vb = value + ((size_t)n * 4096) * 256 + g * 32 + l * 4;
  const int bix = (pi * 8 + g) * 9;
  float a0 = 0.f, a1 = 0.f, a2 = 0.f, a3 = 0.f;
#pragma unroll
  for (int k = 0; k < 9; k++) {
    f32x4 wv = wgt[bix + k];
    i32x4 av = adr[bix + k];
    us4 q0 = *(const us4*)(vb + av[0]);
    us4 q1 = *(const us4*)(vb + av[1]);
    us4 q2 = *(const us4*)(vb + av[2]);
    us4 q3 = *(const us4*)(vb + av[3]);
    a0 += wv[0] * bf2f(q0[0]) + wv[1] * bf2f(q1[0]) + wv[2] * bf2f(q2[0]) + wv[3] * bf2f(q3[0]);
    a1 += wv[0] * bf2f(q0[1]) + wv[1] * bf2f(q1[1]) + wv[2] * bf2f(q2[1]) + wv[3] * bf2f(q3[1]);
    a2 += wv[0] * bf2f(q0[2]) + wv[1] * bf2f(q1[2]) + wv[2] * bf2f(q2[2]) + wv[3] * bf2f(q3[2]);
    a3 += wv[0] * bf2f(q0[3]) + wv[1] * bf2f(q1[3]) + wv[2] * bf2f(q2[3]) + wv[3] * bf2f(q3[3]);
  }
  us4 o;
  o[0] = f2bf(a0); o[1] = f2bf(a1); o[2] = f2bf(a2); o[3] = f2bf(a3);
  *(us4*)&out[((size_t)(n * 4096 + p)) * 256 + g * 32 + l * 4] = o;
}

// ---------------------------------------------------------------------------
// PREP: NCHW->tokens transpose (blocks 0..1023) + all weight conversions.
// ---------------------------------------------------------------------------
__global__ __launch_bounds__(256) void prep_k(
    const float* __restrict__ x, unsigned short* __restrict__ xt,
    const float* __restrict__ c1, unsigned short* __restrict__ o1,
    const float* __restrict__ c2, unsigned short* __restrict__ o2,
    const float* __restrict__ a0, unsigned short* __restrict__ b0,
    const float* __restrict__ a1, unsigned short* __restrict__ b1,
    const float* __restrict__ a2, unsigned short* __restrict__ b2,
    const float* __restrict__ a3, unsigned short* __restrict__ b3,
    const float* __restrict__ a4, unsigned short* __restrict__ b4,
    uint32* __restrict__ zp) {
  __shared__ float lds[64][65];
  int b = blockIdx.x;
  const int t = threadIdx.x;
  if (b == 0 && t < 32) zp[t] = 0u;
  if (b < 1024) {
    const int p0 = (b & 63) * 64, c0 = ((b >> 6) & 3) * 64, n = b >> 8;
    const int pp = t & 63, ccb = t >> 6;
    const float* xb = x + ((size_t)n * 256 + c0) * 4096 + p0;
#pragma unroll
    for (int i = 0; i < 16; i++) {
      int cc = ccb * 16 + i;
      lds[pp][cc] = xb[(size_t)cc * 4096 + pp];
    }
    __syncthreads();
#pragma unroll
    for (int i = 0; i < 2; i++) {
      int pp2 = (t >> 3) + i * 32;
      int c8 = (t & 7) * 8;
      us8 v;
#pragma unroll
      for (int j = 0; j < 8; j++) v[j] = f2bf(lds[pp2][c8 + j]);
      *(us8*)&xt[((size_t)(n * 4096 + p0 + pp2)) * 256 + c0 + c8] = v;
    }
    return;
  }
  int idx = (b - 1024) * 256 + t;
  if (idx < 294912) {
    int ci = idx & 255, r = idx >> 8;
    int tap = r % 9, co = r / 9;
    o1[idx] = f2bf(c1[((size_t)co * 256 + ci) * 9 + tap]);
    return;
  }
  idx -= 294912;
  if (idx < 294912) {
    int ci = idx & 127, r = idx >> 7;
    int tap = r % 9, co = r / 9;
    o2[idx] = f2bf(c2[((size_t)co * 128 + ci) * 9 + tap]);
    return;
  }
  idx -= 294912;
  const float* s;
  unsigned short* d;
  int off;
  if (idx < 65536)       { s = a0; d = b0; off = idx; }
  else if (idx < 120832) { s = a1; d = b1; off = idx - 65536; }
  else if (idx < 186368) { s = a2; d = b2; off = idx - 120832; }
  else if (idx < 382976) { s = a3; d = b3; off = idx - 186368; }
  else if (idx < 579584) { s = a4; d = b4; off = idx - 382976; }
  else return;
  d[off] = f2bf(s[off]);
}

// ---------------------------------------------------------------------------
// S1: conv1 split-K x4 (blocks 0..511, f32 partials) ∪ val/om (512..1023).
// ---------------------------------------------------------------------------
__global__ __launch_bounds__(256) void fused_s1(
    const unsigned short* __restrict__ xt,
    const unsigned short* __restrict__ wc1, float* __restrict__ part,
    const unsigned short* __restrict__ wval, const float* __restrict__ val_b,
    const float* __restrict__ om_b, float* __restrict__ omf,
    unsigned short* __restrict__ valt, const unsigned short* __restrict__ zpage) {
  __shared__ bf16x8 smem[2048];
  int b = blockIdx.x;
  if (b < 512) {
    int s = b >> 7, mt = b & 127;
    gemm_body<7, 256, 128>(mt * 128, 0, s * 576, 576, xt, wc1, nullptr, 2304,
                           128, part + (size_t)s * 2097152, nullptr, nullptr,
                           nullptr, nullptr, zpage, smem);
  } else {
    b -= 512;
    gemm_body<5, 0, 128>((b >> 2) * 128, (b & 3) * 128, 0, 256, xt, wval, val_b,
                         256, 472, valt, om_b, (const float*)omf, nullptr,
                         nullptr, zpage, smem);
  }
}

// ---------------------------------------------------------------------------
// R: y1 reduce+BN+SiLU (blocks 0..1023) ∪ dcn core (1024..5119).
// ---------------------------------------------------------------------------
__global__ __launch_bounds__(256) void fused_r(
    const float* __restrict__ part, const float* __restrict__ g1,
    const float* __restrict__ bb1, const float* __restrict__ m1,
    const float* __restrict__ v1, unsigned short* __restrict__ y1t,
    const unsigned short* __restrict__ valt, const float* __restrict__ omf,
    unsigned short* __restrict__ dcnt) {
  __shared__ char rsm[9216];
  int b = blockIdx.x;
  if (b < 1024) {
    int idx = b * 256 + threadIdx.x;       // 262144 total
    int grow = idx >> 4;
    int co8 = (idx & 15) * 8;
    size_t base = (size_t)grow * 128 + co8;
    f32x4 s0 = *(const f32x4*)&part[base];
    f32x4 s1 = *(const f32x4*)&part[base + 4];
#pragma unroll
    for (int s = 1; s < 4; s++) {
      s0 += *(const f32x4*)&part[base + (size_t)s * 2097152];
      s1 += *(const f32x4*)&part[base + (size_t)s * 2097152 + 4];
    }
    us8 o;
#pragma unroll
    for (int j = 0; j < 8; j++) {
      int co = co8 + j;
      float sc = g1[co] * rsqrtf(v1[co] + EPSV);
      float tt = bb1[co] - m1[co] * sc;
      float v = (j < 4) ? s0[j] : s1[j - 4];
      o[j] = f2bf(silu_f(v * sc + tt));
    }
    *(us8*)&y1t[base] = o;
  } else {
    dcn_body(b - 1024, valt, omf, dcnt, (void*)rsm);
  }
}

// ---------------------------------------------------------------------------
// S2: conv2 BN=64 (blocks 0..511) ∪ outp BN=64 (512..1023).
// ---------------------------------------------------------------------------
__global__ __launch_bounds__(256) void fused_s2(
    const unsigned short* __restrict__ y1t,
    const unsigned short* __restrict__ wc2, const float* __restrict__ g2,
    const float* __restrict__ bb2, const float* __restrict__ m2,
    const float* __restrict__ v2, unsigned short* __restrict__ y2t,
    const unsigned short* __restrict__ dcnt, const unsigned short* __restrict__ woutp,
    const float* __restrict__ outp_b, const float* __restrict__ g3,
    const float* __restrict__ bb3, const float* __restrict__ m3,
    const float* __restrict__ v3, unsigned short* __restrict__ d1t,
    const unsigned short* __restrict__ zpage) {
  __shared__ bf16x8 smem[1536];
  int b = blockIdx.x;
  if (b < 512) {
    gemm_body<2, 128, 64>((b >> 2) * 128, (b & 3) * 64, 0, 1152, y1t, wc2,
                          nullptr, 1152, 256, y2t, g2, bb2, m2, v2, zpage, smem);
  } else {
    b -= 512;
    gemm_body<3, 0, 64>((b >> 2) * 128, (b & 3) * 64, 0, 256, dcnt, woutp,
                        outp_b, 256, 256, d1t, g3, bb3, m3, v3, zpage, smem);
  }
}

// ---------------------------------------------------------------------------
// Standalone GEMM wrapper.
// ---------------------------------------------------------------------------
template <int EPI, int CIN, int BN>
__global__ __launch_bounds__(256) void gemm_k(
    const unsigned short* __restrict__ A, const unsigned short* __restrict__ Bw,
    const float* __restrict__ bias, int K, int Co, void* __restrict__ outv,
    const float* __restrict__ e0, const float* __restrict__ e1,
    const float* __restrict__ e2, const float* __restrict__ e3,
    const unsigned short* __restrict__ zpage) {
  __shared__ bf16x8 smem[2 * (512 + BN * 4)];
  gemm_body<EPI, CIN, BN>(blockIdx.y * 128, blockIdx.x * BN, 0, K, A, Bw, bias,
                          K, Co, outv, e0, e1, e2, e3, zpage, smem);
}

// ---------------------------------------------------------------------------
extern "C" void kernel_launch(void* const* d_in, const int* in_sizes, int n_in,
                              void* d_out, int out_size, void* d_ws,
                              size_t ws_size, hipStream_t stream) {
  const float* x      = (const float*)d_in[0];
  const float* cv1_w  = (const float*)d_in[1];
  const float* cv1_g  = (const float*)d_in[2];
  const float* cv1_b  = (const float*)d_in[3];
  const float* cv1_m  = (const float*)d_in[4];
  const float* cv1_v  = (const float*)d_in[5];
  const float* cv2_w  = (const float*)d_in[6];
  const float* cv2_g  = (const float*)d_in[7];
  const float* cv2_b  = (const float*)d_in[8];
  const float* cv2_m  = (const float*)d_in[9];
  const float* cv2_v  = (const float*)d_in[10];
  const float* val_w  = (const float*)d_in[11];
  const float* val_b  = (const float*)d_in[12];
  const float* om_w   = (const float*)d_in[13];
  const float* om_b   = (const float*)d_in[14];
  const float* outp_w = (const float*)d_in[15];
  const float* outp_b = (const float*)d_in[16];
  const float* bn3_g  = (const float*)d_in[17];
  const float* bn3_b  = (const float*)d_in[18];
  const float* bn3_m  = (const float*)d_in[19];
  const float* bn3_v  = (const float*)d_in[20];
  const float* pw1_w  = (const float*)d_in[21];
  const float* pw1_b  = (const float*)d_in[22];
  const float* pw2_w  = (const float*)d_in[23];
  const float* pw2_b  = (const float*)d_in[24];
  float* out = (float*)d_out;

  char* w = (char*)d_ws;
  auto alloc = [&](size_t bytes) {
    char* p = w;
    w += (bytes + 255) & ~(size_t)255;
    return p;
  };
  unsigned short* xt    = (unsigned short*)alloc(16384ull * 256 * 2);
  unsigned short* y1t   = (unsigned short*)alloc(16384ull * 128 * 2);
  unsigned short* y2t   = (unsigned short*)alloc(16384ull * 256 * 2);
  unsigned short* valt  = (unsigned short*)alloc(16384ull * 256 * 2);
  float*          omf   = (float*)alloc(16384ull * 216 * 4);
  unsigned short* dcnt  = (unsigned short*)alloc(16384ull * 256 * 2);
  unsigned short* d1t   = (unsigned short*)alloc(16384ull * 256 * 2);  // 8 MB
  unsigned short* p1t   = (unsigned short*)alloc(16384ull * 768 * 2);  // 24 MB
  // conv1 split-K partials (32 MB) alias d1t+p1t (dead until S2/S3):
  float* part = (float*)d1t;
  unsigned short* wc1   = (unsigned short*)alloc(128ull * 2304 * 2);
  unsigned short* wc2   = (unsigned short*)alloc(256ull * 1152 * 2);
  // wval and wom MUST be contiguous (fused val/om B-matrix, 472 x 256):
  unsigned short* wval  = (unsigned short*)alloc(256ull * 256 * 2);   // 256-mult
  unsigned short* wom   = (unsigned short*)alloc(216ull * 256 * 2);   // = wval + 65536
  unsigned short* woutp = (unsigned short*)alloc(256ull * 256 * 2);
  unsigned short* wpw1  = (unsigned short*)alloc(768ull * 256 * 2);
  unsigned short* wpw2  = (unsigned short*)alloc(256ull * 768 * 2);
  unsigned short* zpage = (unsigned short*)alloc(256);  // 64B zeros (+pad)

  // prep: tokens + weight conversions
  prep_k<<<5592, 256, 0, stream>>>(x, xt, cv1_w, wc1, cv2_w, wc2, val_w, wval,
                                   om_w, wom, outp_w, woutp, pw1_w, wpw1,
                                   pw2_w, wpw2, (uint32*)zpage);

  // S1: conv1 split-K4 -> partials ∪ val/om projection
  fused_s1<<<1024, 256, 0, stream>>>(xt, wc1, part, wval, val_b, om_b, omf,
                                     valt, zpage);

  // R: y1 reduce+BN+SiLU ∪ dcn core
  fused_r<<<5120, 256, 0, stream>>>(part, cv1_g, cv1_b, cv1_m, cv1_v, y1t,
                                    valt, omf, dcnt);

  // S2: conv2 ∪ outp
  fused_s2<<<1024, 256, 0, stream>>>(y1t, wc2, cv2_g, cv2_b, cv2_m, cv2_v, y2t,
                                     dcnt, woutp, outp_b, bn3_g, bn3_b, bn3_m,
                                     bn3_v, d1t, zpage);

  // pw1 (768 blocks), pw2 + residual (512 blocks)
  gemm_k<4, 0, 128><<<dim3(6, 128), 256, 0, stream>>>(
      d1t, wpw1, pw1_b, 256, 768, p1t, nullptr, nullptr, nullptr, nullptr, zpage);
  gemm_k<6, 0, 64><<<dim3(4, 128), 256, 0, stream>>>(
      p1t, wpw2, pw2_b, 768, 256, out, x, (const float*)y2t, nullptr, nullptr, zpage);
}